// Round 1
// baseline (438.692 us; speedup 1.0000x reference)
//
#include <hip/hip_runtime.h>

// Problem constants (from reference):
//   x:           [128, 8, 32, 32, 32]  f32
//   conv_weight: [16, 8, 3, 3, 3]      f32
//   conv_bias:   [16]                  f32
//   bias:        [16,1,1,1] -> 16      f32
//   out:         [128,1,1,1] -> 128    f32
//
// Math identity used:
//   out[b] = (1/6750) * sum_{c, pooled cells} max_{2x2x2}(conv_raw[b,c,...])
//            + sum_c (conv_bias[c]*0.5 + bias[c])
// (conv_bias add and /2 commute with max; mean+channel-sum separate linearly)

__global__ __launch_bounds__(256) void conv_pool_partial(
    const float* __restrict__ x,
    const float* __restrict__ cw,
    float* __restrict__ partial) {
  const int pd = blockIdx.x;   // pooled d: 0..14
  const int co = blockIdx.y;   // out channel: 0..15
  const int b  = blockIdx.z;   // batch: 0..127
  const int t  = threadIdx.x;  // 0..255; 225 active (15x15 pooled h,w)

  float m = 0.0f;
  if (t < 225) {
    const int ph = t / 15;
    const int pw = t - ph * 15;
    const int d0 = pd * 2, h0 = ph * 2, w0 = pw * 2;

    float acc[2][2][2] = {};  // [od][oh][ow] conv outputs of this pooled cell

    for (int ci = 0; ci < 8; ++ci) {
      // Weights: block-uniform addresses -> scalar loads / SGPRs.
      const float* wp = cw + (co * 8 + ci) * 27;
      float wt[27];
#pragma unroll
      for (int i = 0; i < 27; ++i) wt[i] = wp[i];

      const float* xp =
          x + ((((size_t)b * 8 + ci) * 32 + d0) * 32 + h0) * 32 + w0;

#pragma unroll
      for (int dd = 0; dd < 4; ++dd) {
#pragma unroll
        for (int hh = 0; hh < 4; ++hh) {
          const float* row = xp + dd * 1024 + hh * 32;
          // w0 is even -> 8B aligned: two float2 loads
          const float2 p0 = *reinterpret_cast<const float2*>(row);
          const float2 p1 = *reinterpret_cast<const float2*>(row + 2);
          const float xv0 = p0.x, xv1 = p0.y, xv2 = p1.x, xv3 = p1.y;

#pragma unroll
          for (int od = 0; od < 2; ++od) {
            const int kd = dd - od;
            if (kd < 0 || kd > 2) continue;
#pragma unroll
            for (int oh = 0; oh < 2; ++oh) {
              const int kh = hh - oh;
              if (kh < 0 || kh > 2) continue;
              const float w0v = wt[(kd * 3 + kh) * 3 + 0];
              const float w1v = wt[(kd * 3 + kh) * 3 + 1];
              const float w2v = wt[(kd * 3 + kh) * 3 + 2];
              acc[od][oh][0] =
                  fmaf(w0v, xv0, fmaf(w1v, xv1, fmaf(w2v, xv2, acc[od][oh][0])));
              acc[od][oh][1] =
                  fmaf(w0v, xv1, fmaf(w1v, xv2, fmaf(w2v, xv3, acc[od][oh][1])));
            }
          }
        }
      }
    }

    // max over the 2x2x2 window
    m = acc[0][0][0];
    m = fmaxf(m, acc[0][0][1]);
    m = fmaxf(m, acc[0][1][0]);
    m = fmaxf(m, acc[0][1][1]);
    m = fmaxf(m, acc[1][0][0]);
    m = fmaxf(m, acc[1][0][1]);
    m = fmaxf(m, acc[1][1][0]);
    m = fmaxf(m, acc[1][1][1]);
  }

  // block-wide sum of m (inactive threads contribute 0)
#pragma unroll
  for (int off = 32; off > 0; off >>= 1) m += __shfl_down(m, off);
  __shared__ float red[4];
  if ((t & 63) == 0) red[t >> 6] = m;
  __syncthreads();
  if (t == 0) {
    partial[((size_t)b * 16 + co) * 15 + pd] = red[0] + red[1] + red[2] + red[3];
  }
}

__global__ __launch_bounds__(256) void finalize_kernel(
    const float* __restrict__ partial,
    const float* __restrict__ conv_bias,
    const float* __restrict__ bias,
    float* __restrict__ out) {
  const int b = blockIdx.x;
  const int t = threadIdx.x;
  float s = (t < 240) ? partial[(size_t)b * 240 + t] : 0.0f;
#pragma unroll
  for (int off = 32; off > 0; off >>= 1) s += __shfl_down(s, off);
  __shared__ float red[4];
  if ((t & 63) == 0) red[t >> 6] = s;
  __syncthreads();
  if (t == 0) {
    float k = 0.0f;
#pragma unroll
    for (int c = 0; c < 16; ++c) k += conv_bias[c] * 0.5f + bias[c];
    out[b] = (red[0] + red[1] + red[2] + red[3]) * (1.0f / 6750.0f) + k;
  }
}

extern "C" void kernel_launch(void* const* d_in, const int* in_sizes, int n_in,
                              void* d_out, int out_size, void* d_ws, size_t ws_size,
                              hipStream_t stream) {
  const float* x    = (const float*)d_in[0];
  const float* cw   = (const float*)d_in[1];
  const float* cb   = (const float*)d_in[2];
  const float* bias = (const float*)d_in[3];
  float* out = (float*)d_out;
  float* partial = (float*)d_ws;  // 128*16*15 = 30720 floats = 120 KiB

  conv_pool_partial<<<dim3(15, 16, 128), 256, 0, stream>>>(x, cw, partial);
  finalize_kernel<<<128, 256, 0, stream>>>(partial, cb, bias, out);
}

// Round 2
// 64.551 us; speedup vs baseline: 6.7961x; 6.7961x over previous
//
#include <hip/hip_runtime.h>

// x:  [128, 8, 32, 32, 32] f32   cw: [16,8,3,3,3] f32   cb: [16]   bias: [16]
// out[b] = (1/6750)*sum_{c,cells} maxpool2(conv_raw)[b,c,cell] + sum_c(cb[c]/2 + bias[c])
//
// Implicit GEMM on MFMA: per block (b, pd): stage x[b, :, 2pd..2pd+3, :, :] to LDS
// as bf16 [d][h][w][ci]; GEMM M=16 ow, N=16 co, K=216 (27 taps x 8 ci, 4 taps/mfma).

using short8 = __attribute__((ext_vector_type(8))) short;
using f32x4  = __attribute__((ext_vector_type(4))) float;

__device__ __forceinline__ unsigned short f2bf(float f) {
  unsigned u = __float_as_uint(f);
  return (unsigned short)((u + 0x7FFFu + ((u >> 16) & 1u)) >> 16);
}

// Reorder conv weights into per-lane MFMA B fragments (bf16).
// Bp[g][lane][j] = w[co=lane&15][ci=j][tap=4g+(lane>>4)], tap>=27 -> 0.
__global__ __launch_bounds__(256) void prep_w(const float* __restrict__ cw,
                                              short* __restrict__ Bp) {
  int i = threadIdx.x + blockIdx.x * 256;  // 0..447 = 7 groups * 64 lanes
  if (i >= 448) return;
  int g = i >> 6, l = i & 63;
  int co = l & 15, tt = l >> 4;
  int tap = 4 * g + tt;
  short8 o;
#pragma unroll
  for (int j = 0; j < 8; ++j) {
    float v = (tap < 27) ? cw[(co * 8 + j) * 27 + tap] : 0.0f;
    o[j] = (short)f2bf(v);
  }
  *(short8*)(Bp + (size_t)i * 8) = o;
}

__global__ __launch_bounds__(256) void conv_mfma(const float* __restrict__ x,
                                                 const short* __restrict__ Bp,
                                                 float* __restrict__ partial) {
  __shared__ __align__(16) short xs[4 * 32 * 32 * 8];  // 64 KiB: [d][h][w][ci]
  const int pd = blockIdx.x;  // 0..14
  const int b  = blockIdx.y;  // 0..127
  const int t  = threadIdx.x;
  const int d0 = pd * 2;

  // ---- stage global f32 -> LDS bf16, transposed to ci-fastest ----
  {
    const float* xb = x + (size_t)b * 8 * 32768;
    for (int s = t; s < 1024; s += 256) {  // 1024 float4-sites: [d(4)][h(32)][wc(8)]
      int d = s >> 8, h = (s >> 3) & 31, wc = s & 7;
      float va[8][4];
#pragma unroll
      for (int ci = 0; ci < 8; ++ci) {
        const float4 v = *(const float4*)(xb + ((size_t)ci * 32 + d0 + d) * 1024 +
                                          h * 32 + wc * 4);
        va[ci][0] = v.x; va[ci][1] = v.y; va[ci][2] = v.z; va[ci][3] = v.w;
      }
      int base = ((d * 32 + h) * 32 + wc * 4) * 8;
#pragma unroll
      for (int wi = 0; wi < 4; ++wi) {
        short8 o;
#pragma unroll
        for (int ci = 0; ci < 8; ++ci) o[ci] = (short)f2bf(va[ci][wi]);
        *(short8*)(xs + base + wi * 8) = o;
      }
    }
  }

  const int lane = t & 63, wv = t >> 6;

  // ---- B fragments (coalesced, block-invariant) ----
  short8 Bf[7];
#pragma unroll
  for (int g = 0; g < 7; ++g)
    Bf[g] = *(const short8*)(Bp + ((size_t)g * 64 + lane) * 8);

  // ---- per-lane A-fragment LDS offsets (short units) ----
  const int m = lane & 15, tg = lane >> 4;
  int pre0[7], pre1[7];
#pragma unroll
  for (int g = 0; g < 7; ++g) {
    int tap = 4 * g + tg;
    if (tap >= 27) tap = 0;  // dup tap; its B weights are 0
    int kd = tap / 9, r = tap % 9, kh = r / 3, kw = r % 3;
    int w0 = m + kw;             // chunk0: ow 0..15
    int w1 = w0 + 16;            // chunk1: ow 16..31 (30,31 discarded)
    if (w1 > 31) w1 = 31;        // clamp: only affects discarded rows
    pre0[g] = (kd * 1024 + kh * 32 + w0) * 8;
    pre1[g] = (kd * 1024 + kh * 32 + w1) * 8;
  }

  __syncthreads();

  // ---- compute: 30 tasks (q=pooled-h 0..14, chunk 0..1), 4 waves round-robin ----
  float sum = 0.0f;
  for (int tid = wv; tid < 30; tid += 4) {
    int q = tid >> 1, c = tid & 1;
    int ohoff = (2 * q) * 256;  // oh0 * h-stride(32*8)
    f32x4 cc[2][2] = {};        // [od][s] conv tiles (16 ow x 16 co)
#pragma unroll
    for (int g = 0; g < 7; ++g) {
      int pg = (c ? pre1[g] : pre0[g]) + ohoff;
#pragma unroll
      for (int od = 0; od < 2; ++od) {
#pragma unroll
        for (int s = 0; s < 2; ++s) {
          short8 a = *(const short8*)(xs + pg + od * 8192 + s * 256);
          cc[od][s] =
              __builtin_amdgcn_mfma_f32_16x16x32_bf16(a, Bf[g], cc[od][s], 0, 0, 0);
        }
      }
    }
    // maxpool 2x2x2: od x s x (row-pair within lane), then masked sum
#pragma unroll
    for (int p = 0; p < 2; ++p) {
      float v = fmaxf(fmaxf(fmaxf(cc[0][0][2 * p], cc[0][0][2 * p + 1]),
                            fmaxf(cc[0][1][2 * p], cc[0][1][2 * p + 1])),
                      fmaxf(fmaxf(cc[1][0][2 * p], cc[1][0][2 * p + 1]),
                            fmaxf(cc[1][1][2 * p], cc[1][1][2 * p + 1])));
      bool inval = (c == 1) && (tg == 3) && (p == 1);  // ow pair (30,31)
      sum += inval ? 0.0f : v;
    }
  }

  // ---- block reduction -> one partial ----
#pragma unroll
  for (int off = 32; off; off >>= 1) sum += __shfl_down(sum, off);
  __syncthreads();  // all waves done with xs
  float* red = (float*)xs;
  if ((t & 63) == 0) red[t >> 6] = sum;
  __syncthreads();
  if (t == 0) partial[b * 15 + pd] = red[0] + red[1] + red[2] + red[3];
}

__global__ __launch_bounds__(64) void finalize(const float* __restrict__ partial,
                                               const float* __restrict__ cb,
                                               const float* __restrict__ bias,
                                               float* __restrict__ out) {
  const int b = blockIdx.x, t = threadIdx.x;
  float s = (t < 15) ? partial[b * 15 + t] : 0.0f;
#pragma unroll
  for (int off = 32; off; off >>= 1) s += __shfl_down(s, off);
  if (t == 0) {
    float k = 0.0f;
#pragma unroll
    for (int c = 0; c < 16; ++c) k += cb[c] * 0.5f + bias[c];
    out[b] = s * (1.0f / 6750.0f) + k;
  }
}

extern "C" void kernel_launch(void* const* d_in, const int* in_sizes, int n_in,
                              void* d_out, int out_size, void* d_ws, size_t ws_size,
                              hipStream_t stream) {
  const float* x    = (const float*)d_in[0];
  const float* cw   = (const float*)d_in[1];
  const float* cb   = (const float*)d_in[2];
  const float* bias = (const float*)d_in[3];
  float* out = (float*)d_out;

  short* Bp      = (short*)d_ws;                       // 448*8 bf16 = 7168 B
  float* partial = (float*)((char*)d_ws + 8192);       // 1920 floats

  prep_w<<<2, 256, 0, stream>>>(cw, Bp);
  conv_mfma<<<dim3(15, 128), 256, 0, stream>>>(x, Bp, partial);
  finalize<<<128, 64, 0, stream>>>(partial, cb, bias, out);
}

// Round 3
// 45.419 us; speedup vs baseline: 9.6587x; 1.4212x over previous
//
#include <hip/hip_runtime.h>

// x: [128,8,32,32,32] f32  cw: [16,8,3,3,3] f32  cb: [16]  bias: [16]  out: [128]
// out[b] = (1/6750)*sum_{c,cells} maxpool2(conv_raw) + sum_c(cb[c]/2 + bias[c])
//
// MFMA implicit GEMM, (kd,kh)-uniform K-bundles (tg = kw, tg==3 zero-pad):
// one A-fragment F(plane=kd+od, row=2q+s+kh) serves up to 4 mfma -> 16 ds_reads
// per 36 mfma per task. LDS XOR-swizzled (byte ^= ((w>>3)&3)<<4) on both sides.

using short8 = __attribute__((ext_vector_type(8))) short;
using f32x4  = __attribute__((ext_vector_type(4))) float;

__device__ __forceinline__ unsigned short f2bf(float f) {
  unsigned u = __float_as_uint(f);
  return (unsigned short)((u + 0x7FFFu + ((u >> 16) & 1u)) >> 16);
}

// Bp[g=kd*3+kh][lane]: 8 bf16 = w[co=lane&15][ci=j][kd][kh][kw=lane>>4]; kw==3 -> 0
__global__ __launch_bounds__(256) void prep_w(const float* __restrict__ cw,
                                              short* __restrict__ Bp) {
  int i = threadIdx.x + blockIdx.x * 256;
  if (i >= 576) return;
  int g = i >> 6, l = i & 63;
  int co = l & 15, kw = l >> 4;
  int kd = g / 3, kh = g % 3;
  short8 o;
#pragma unroll
  for (int j = 0; j < 8; ++j) {
    float v = (kw < 3) ? cw[(co * 8 + j) * 27 + kd * 9 + kh * 3 + kw] : 0.0f;
    o[j] = (short)f2bf(v);
  }
  *(short8*)(Bp + (size_t)i * 8) = o;
}

__global__ __launch_bounds__(512, 4) void conv_mfma(const float* __restrict__ x,
                                                    const short* __restrict__ Bp,
                                                    float* __restrict__ partial) {
  __shared__ __align__(16) short xs[32768];  // 64 KiB; byte=((d*1024+h*32+w)*16)^swz(w)
  __shared__ float red[8];
  // XCD-chunked swizzle: 1920 blocks, 1920%8==0 -> simple bijective form
  const int flat = blockIdx.x;
  const int swz = (flat & 7) * 240 + (flat >> 3);
  const int pd = swz % 15, b = swz / 15;
  const int t = threadIdx.x;
  const int d0 = pd * 2;
  char* xc = (char*)xs;

  // ---- stage x[b, :, d0..d0+3, :, :] -> LDS bf16 [d][h][w][ci], swizzled ----
  {
    const float* xb = x + (size_t)b * 262144;  // 8*32768
    for (int s = t; s < 1024; s += 512) {      // sites: [d(4)][h(32)][wc(8)]
      const int d = s >> 8, h = (s >> 3) & 31, wc = s & 7;
      float4 va[8];
#pragma unroll
      for (int ci = 0; ci < 8; ++ci)
        va[ci] = *(const float4*)(x + (size_t)b * 262144 + (size_t)ci * 32768 +
                                  (d0 + d) * 1024 + h * 32 + wc * 4);
      (void)xb;
#pragma unroll
      for (int wi = 0; wi < 4; ++wi) {
        const int w = wc * 4 + wi;
        short8 o;
#pragma unroll
        for (int ci = 0; ci < 8; ++ci)
          o[ci] = (short)f2bf(((const float*)&va[ci])[wi]);
        const int byte = ((d * 1024 + h * 32 + w) * 16) ^ (((w >> 3) & 3) << 4);
        *(short8*)(xc + byte) = o;
      }
    }
  }

  const int lane = t & 63, wv = t >> 6;

  // ---- B fragments: 9 groups (kd,kh) ----
  short8 Bw[9];
#pragma unroll
  for (int g = 0; g < 9; ++g)
    Bw[g] = *(const short8*)(Bp + ((size_t)g * 64 + lane) * 8);

  // ---- per-lane A base addresses (w = m + kw(tg), chunk1 +16, clamped) ----
  const int m = lane & 15, tg = lane >> 4;
  const int w0 = m + tg;
  int w1 = m + 16 + tg;
  if (w1 > 31) w1 = 31;  // only pad-tap or discarded rows clamp (verified)
  const int wb0 = (w0 * 16) ^ (((w0 >> 3) & 3) << 4);
  const int wb1 = (w1 * 16) ^ (((w1 >> 3) & 3) << 4);

  __syncthreads();

  // ---- 30 tasks (q=0..14 pooled-h, c=ow chunk), 8 waves round-robin ----
  float sum = 0.0f;
  for (int tid = wv; tid < 30; tid += 8) {
    const int q = tid >> 1, c = tid & 1;
    const int base = (c ? wb1 : wb0) + q * 1024;  // row=2q -> 2q*512 bytes
    f32x4 cc[2][2] = {};  // [od][s=oh-2q], 16 ow x 16 co each
#pragma unroll
    for (int p = 0; p < 4; ++p) {  // input plane (rel)
#pragma unroll
      for (int r = 0; r < 4; ++r) {  // input row offset
        const short8 a = *(const short8*)(xc + base + p * 16384 + r * 512);
        if (p < 3 && r < 3)
          cc[0][0] = __builtin_amdgcn_mfma_f32_16x16x32_bf16(a, Bw[p * 3 + r], cc[0][0], 0, 0, 0);
        if (p < 3 && r > 0)
          cc[0][1] = __builtin_amdgcn_mfma_f32_16x16x32_bf16(a, Bw[p * 3 + r - 1], cc[0][1], 0, 0, 0);
        if (p > 0 && r < 3)
          cc[1][0] = __builtin_amdgcn_mfma_f32_16x16x32_bf16(a, Bw[(p - 1) * 3 + r], cc[1][0], 0, 0, 0);
        if (p > 0 && r > 0)
          cc[1][1] = __builtin_amdgcn_mfma_f32_16x16x32_bf16(a, Bw[(p - 1) * 3 + r - 1], cc[1][1], 0, 0, 0);
      }
    }
    // maxpool 2x2x2 (od, s, ow-pair in C rows), mask ow 30/31 of chunk1
#pragma unroll
    for (int p2 = 0; p2 < 2; ++p2) {
      float v = fmaxf(fmaxf(fmaxf(cc[0][0][2 * p2], cc[0][0][2 * p2 + 1]),
                            fmaxf(cc[0][1][2 * p2], cc[0][1][2 * p2 + 1])),
                      fmaxf(fmaxf(cc[1][0][2 * p2], cc[1][0][2 * p2 + 1]),
                            fmaxf(cc[1][1][2 * p2], cc[1][1][2 * p2 + 1])));
      const bool inval = (c == 1) && (tg == 3) && (p2 == 1);
      sum += inval ? 0.0f : v;
    }
  }

  // ---- block reduction ----
#pragma unroll
  for (int off = 32; off; off >>= 1) sum += __shfl_down(sum, off);
  if (lane == 0) red[wv] = sum;
  __syncthreads();
  if (t == 0) {
    float s2 = 0.0f;
#pragma unroll
    for (int wvi = 0; wvi < 8; ++wvi) s2 += red[wvi];
    partial[b * 15 + pd] = s2;
  }
}

__global__ __launch_bounds__(64) void finalize(const float* __restrict__ partial,
                                               const float* __restrict__ cb,
                                               const float* __restrict__ bias,
                                               float* __restrict__ out) {
  const int b = blockIdx.x, t = threadIdx.x;
  float s = (t < 15) ? partial[b * 15 + t] : 0.0f;
#pragma unroll
  for (int off = 32; off; off >>= 1) s += __shfl_down(s, off);
  if (t == 0) {
    float k = 0.0f;
#pragma unroll
    for (int c = 0; c < 16; ++c) k += cb[c] * 0.5f + bias[c];
    out[b] = s * (1.0f / 6750.0f) + k;
  }
}

extern "C" void kernel_launch(void* const* d_in, const int* in_sizes, int n_in,
                              void* d_out, int out_size, void* d_ws, size_t ws_size,
                              hipStream_t stream) {
  const float* x    = (const float*)d_in[0];
  const float* cw   = (const float*)d_in[1];
  const float* cb   = (const float*)d_in[2];
  const float* bias = (const float*)d_in[3];
  float* out = (float*)d_out;

  short* Bp      = (short*)d_ws;                  // 576*8 bf16 = 9216 B
  float* partial = (float*)((char*)d_ws + 16384); // 1920 floats

  prep_w<<<3, 256, 0, stream>>>(cw, Bp);
  conv_mfma<<<1920, 512, 0, stream>>>(x, Bp, partial);
  finalize<<<128, 64, 0, stream>>>(partial, cb, bias, out);
}